// Round 4
// baseline (35.474 us; speedup 1.0000x reference)
//
#include <hip/hip_runtime.h>

#define POOL 7
#define NPTS 49
#define NBUCKET 256

typedef float f4 __attribute__((ext_vector_type(4)));

__device__ __forceinline__ f4 ld4(const float* p) { return *(const f4*)p; }

__device__ __forceinline__ int roi_level(float dy, float dx) {
    // matches jnp: log2(sqrt(max(h*w,0)) / 0.21875 + 1e-8), round half-even
    const float rl = log2f(sqrtf(fmaxf(dy * dx, 0.0f)) / 0.21875f + 1e-8f);
    int lvl = 4 + (int)rintf(rl);
    return lvl < 3 ? 3 : (lvl > 6 ? 6 : lvl);
}

// Single-block counting sort, one props pass. Key = (batch, level-group,
// y-center/64) -> 256 buckets; consecutive slots are y-adjacent same-level.
__global__ __launch_bounds__(1024) void bucket_kernel(
    const float* __restrict__ props, int* __restrict__ order, int BN, int N)
{
    __shared__ unsigned char keys[2048];
    __shared__ int hist[NBUCKET];
    __shared__ int offs[NBUCKET];
    const int tid = threadIdx.x;
    if (tid < NBUCKET) hist[tid] = 0;
    __syncthreads();
    for (int r = tid; r < BN; r += 1024) {
        const f4 p = ld4(props + (size_t)r * 4);
        const int lvl = roi_level(p.z - p.x, p.w - p.y);
        int lg = lvl - 3; lg = lg < 0 ? 0 : (lg > 1 ? 1 : lg);  // data hits {3,4}
        const float yc = 0.5f * (p.x + p.z);
        int yq = (int)(yc * 64.0f);
        yq = yq < 0 ? 0 : (yq > 63 ? 63 : yq);
        const int b = r >= N ? 1 : 0;
        const int k = (b << 7) | (lg << 6) | yq;
        keys[r] = (unsigned char)k;
        atomicAdd(&hist[k], 1);
    }
    __syncthreads();
    if (tid == 0) {
        int acc = 0;
        for (int i = 0; i < NBUCKET; ++i) { offs[i] = acc; acc += hist[i]; }
    }
    __syncthreads();
    for (int r = tid; r < BN; r += 1024) {
        const int pos = atomicAdd(&offs[keys[r]], 1);
        order[pos] = r;
    }
}

// Persistent: 1024 blocks (4/CU). XCD k's 128 blocks walk its contiguous
// chunk of sorted slots with stride 128 -> live window = 128 consecutive
// y-adjacent same-level ROIs (~3-5 MB) -> L2-resident reads.
__global__ __launch_bounds__(256, 4) void roialign_kernel(
    const float* __restrict__ p3, const float* __restrict__ p4,
    const float* __restrict__ p5, const float* __restrict__ p6,
    const float* __restrict__ props, const int* __restrict__ order,
    float* __restrict__ out, int B, int N, int C, int BN)
{
    const int bid = blockIdx.x;
    const int xcd = bid & 7;           // empirical round-robin blockIdx->XCD
    const int j   = bid >> 3;          // 0..127 within XCD
    // bijective chunk split of BN slots over 8 XCDs
    const int q = BN >> 3, rr = BN & 7;
    const int cs = xcd < rr ? xcd * (q + 1) : rr * (q + 1) + (xcd - rr) * q;
    const int ce = cs + q + (xcd < rr ? 1 : 0);

    const int tid = threadIdx.x;
    const int pl  = tid >> 6;             // point lane 0..3
    const int cg  = (tid & 63) << 2;      // channel offset (float4)

    for (int s = cs + j; s < ce; s += 128) {
        const int roi = order[s];
        const int b   = roi >= N ? 1 : 0;

        const f4 pv = ld4(props + (size_t)roi * 4);
        const float y1 = pv.x, x1 = pv.y, y2 = pv.z, x2 = pv.w;
        const float dy = y2 - y1, dx = x2 - x1;

        const int lvl = roi_level(dy, dx);
        const float* f;
        int H;
        if      (lvl == 3) { f = p3; H = 128; }
        else if (lvl == 4) { f = p4; H = 64;  }
        else if (lvl == 5) { f = p5; H = 32;  }
        else               { f = p6; H = 16;  }
        const int W = H;
        const float hm1 = (float)(H - 1);
        const float* fb = f + (size_t)b * H * W * C;

        const int obase = roi * NPTS * C + cg;

        auto calc = [&](int p, int& o00, int& o01, int& o10, int& o11,
                        float& fx, float& fy) {
            const int py = p / POOL;
            const int px = p - py * POOL;
            const float ys = (y1 + (float)py * (1.0f / (POOL - 1)) * dy) * hm1;
            const float xs = (x1 + (float)px * (1.0f / (POOL - 1)) * dx) * hm1;
            const float y0f = floorf(ys);
            const float x0f = floorf(xs);
            fy = ys - y0f;
            fx = xs - x0f;
            int yA = (int)y0f; yA = yA < 0 ? 0 : (yA > H - 1 ? H - 1 : yA);
            int yB = yA + 1;   yB = yB > H - 1 ? H - 1 : yB;
            int xA = (int)x0f; xA = xA < 0 ? 0 : (xA > W - 1 ? W - 1 : xA);
            int xB = xA + 1;   xB = xB > W - 1 ? W - 1 : xB;
            const int rA = yA * W, rB = yB * W;
            o00 = (rA + xA) * C + cg;
            o01 = (rA + xB) * C + cg;
            o10 = (rB + xA) * C + cg;
            o11 = (rB + xB) * C + cg;
        };

        #pragma unroll
        for (int p0 = 0; p0 < 48; p0 += 8) {
            const int pa = p0 + pl;   // <= 43
            const int pb = pa + 4;    // <= 47
            int a00, a01, a10, a11, b00, b01, b10, b11;
            float afx, afy, bfx, bfy;
            calc(pa, a00, a01, a10, a11, afx, afy);
            calc(pb, b00, b01, b10, b11, bfx, bfy);

            const f4 va00 = ld4(fb + a00), va01 = ld4(fb + a01);
            const f4 va10 = ld4(fb + a10), va11 = ld4(fb + a11);
            const f4 vb00 = ld4(fb + b00), vb01 = ld4(fb + b01);
            const f4 vb10 = ld4(fb + b10), vb11 = ld4(fb + b11);

            const f4 ta = va00 + afx * (va01 - va00);
            const f4 ba = va10 + afx * (va11 - va10);
            const f4 oa = ta + afy * (ba - ta);
            const f4 tb = vb00 + bfx * (vb01 - vb00);
            const f4 bb = vb10 + bfx * (vb11 - vb10);
            const f4 ob = tb + bfy * (bb - tb);

            __builtin_nontemporal_store(oa, (f4*)(out + obase + pa * C));
            __builtin_nontemporal_store(ob, (f4*)(out + obase + pb * C));
        }

        if (pl == 0) {  // tail: point 48
            int o00, o01, o10, o11;
            float fx, fy;
            calc(48, o00, o01, o10, o11, fx, fy);
            const f4 v00 = ld4(fb + o00), v01 = ld4(fb + o01);
            const f4 v10 = ld4(fb + o10), v11 = ld4(fb + o11);
            const f4 t  = v00 + fx * (v01 - v00);
            const f4 bo = v10 + fx * (v11 - v10);
            const f4 o  = t + fy * (bo - t);
            __builtin_nontemporal_store(o, (f4*)(out + obase + 48 * C));
        }
    }
}

extern "C" void kernel_launch(void* const* d_in, const int* in_sizes, int n_in,
                              void* d_out, int out_size, void* d_ws, size_t ws_size,
                              hipStream_t stream) {
    (void)ws_size; (void)n_in; (void)out_size;

    const float* p3 = (const float*)d_in[0];
    const float* p4 = (const float*)d_in[1];
    const float* p5 = (const float*)d_in[2];
    const float* p6 = (const float*)d_in[3];
    const float* props = (const float*)d_in[4];
    float* out = (float*)d_out;
    int* order = (int*)d_ws;

    const int B = 2;
    const int N = in_sizes[4] / (B * 4);          // 1000
    const int C = in_sizes[0] / (B * 128 * 128);  // 256
    const int BN = B * N;

    bucket_kernel<<<1, 1024, 0, stream>>>(props, order, BN, N);
    roialign_kernel<<<1024, 256, 0, stream>>>(p3, p4, p5, p6, props, order,
                                              out, B, N, C, BN);
}